// Round 9
// baseline (133.339 us; speedup 1.0000x reference)
//
#include <hip/hip_runtime.h>
#include <hip/hip_bf16.h>
#include <math.h>

#define B_ 2
#define C_ 64
#define H_ 192
#define W_ 192
#define HW_ (H_*W_)
#define BHW_ (B_*HW_)
#define KK_ 9
#define CK_ (C_*KK_)      // 576
#define KSTEPS_ (CK_/32)  // 18
#define TX_ 12            // W_/16 column tiles

typedef __bf16 bf16x8 __attribute__((ext_vector_type(8)));
typedef float  f32x4  __attribute__((ext_vector_type(4)));
typedef unsigned short ushortx8 __attribute__((ext_vector_type(8)));
typedef unsigned short ushortx4 __attribute__((ext_vector_type(4)));

__device__ __forceinline__ float bf2f(unsigned short u) {
    unsigned int t = ((unsigned int)u) << 16;
    return __builtin_bit_cast(float, t);
}
__device__ __forceinline__ unsigned short f2bf(float f) {
    __hip_bfloat16 hb = __float2bfloat16(f);
    return *reinterpret_cast<unsigned short*>(&hb);
}

// ---------------- LayerNorm over channel axis -> bf16 NHWC ------------------
__global__ void ln_kernel(const float* __restrict__ x,
                          const float* __restrict__ lnw,
                          const float* __restrict__ lnb,
                          unsigned short* __restrict__ xnb) {   // [BHW][64]
    int p = blockIdx.x * blockDim.x + threadIdx.x;
    if (p >= BHW_) return;
    int b = p / HW_, pix = p % HW_;
    const float* xb = x + (size_t)b * C_ * HW_ + pix;
    float v[C_];
    float s = 0.f, s2 = 0.f;
    #pragma unroll
    for (int c = 0; c < C_; ++c) {
        v[c] = xb[(size_t)c * HW_];
        s += v[c]; s2 += v[c] * v[c];
    }
    float mu  = s * (1.0f / C_);
    float var = s2 * (1.0f / C_) - mu * mu;
    float inv = rsqrtf(var + 1e-5f);
    unsigned short* zb = xnb + (size_t)p * 64;
    #pragma unroll
    for (int g = 0; g < 8; ++g) {
        ushortx8 st;
        #pragma unroll
        for (int j = 0; j < 8; ++j) {
            int c = g * 8 + j;
            st[j] = f2bf((v[c] - mu) * inv * lnw[c] + lnb[c]);
        }
        *reinterpret_cast<ushortx8*>(zb + g * 8) = st;
    }
}

// ---------------- weight prepack (tap-outer ck = k*64+c) -------------------
__global__ void prepack_kernel(const float* __restrict__ dw,
                               const float* __restrict__ fw,
                               const float* __restrict__ offw,
                               const float* __restrict__ maskw,
                               unsigned short* __restrict__ wpack,
                               unsigned short* __restrict__ wpf,
                               unsigned short* __restrict__ wpc) {
    const int n1 = 4 * KSTEPS_ * 64 * 8;   // deform
    const int n2 = 4 * KSTEPS_ * 64 * 8;   // fusion
    const int n3 = 2 * KSTEPS_ * 64 * 8;   // conv27
    int gid = blockIdx.x * blockDim.x + threadIdx.x;
    int nth = gridDim.x * blockDim.x;
    for (int idx = gid; idx < n1 + n2 + n3; idx += nth) {
        int which = (idx < n1) ? 0 : (idx < n1 + n2 ? 1 : 2);
        int rem = idx - (which == 0 ? 0 : (which == 1 ? n1 : n1 + n2));
        int j = rem & 7;
        int l = (rem >> 3) & 63;
        int rest = rem >> 9;
        int s = rest % KSTEPS_;
        int t = rest / KSTEPS_;
        int oc = t * 16 + (l & 15);
        int ck = s * 32 + (l >> 4) * 8 + j;
        int k = ck >> 6, c = ck & 63;
        float v;
        if (which == 0) {
            v = dw[(size_t)oc * CK_ + c * 9 + k];
        } else if (which == 1) {
            v = fw[(size_t)oc * CK_ + c * 9 + k];
        } else {
            v = (oc < 18) ? offw[(size_t)oc * CK_ + c * 9 + k]
              : (oc < 27) ? maskw[(size_t)(oc - 18) * CK_ + c * 9 + k]
              : 0.f;
        }
        unsigned short u = f2bf(v);
        if (which == 0) wpack[rem] = u;
        else if (which == 1) wpf[rem] = u;
        else wpc[rem] = u;
    }
}

// ---------------- merged: conv27 + modulated deformable conv ---------------
// 1-wave block = one 16x1 pixel row-segment; consecutive blocks walk rows
// within a 16-wide column strip (L1 halo reuse).
__global__ void __launch_bounds__(64) dc_mfma(
        const unsigned short* __restrict__ xnb,   // NHWC
        const unsigned short* __restrict__ wpc,
        const float* __restrict__ offb, const float* __restrict__ maskb,
        const unsigned short* __restrict__ wpack,
        const float* __restrict__ db,
        unsigned short* __restrict__ xdefb) {     // NHWC
    __shared__ float som[16][36];   // pad 36
    int lane = threadIdx.x;
    int bid  = blockIdx.x;
    int row  = bid % H_;
    int rest = bid / H_;            // b*TX_ + tx
    int tx   = rest % TX_;
    int b    = rest / TX_;
    int pq = lane & 15;
    int kchunk = lane >> 4;
    int h = row, w = tx * 16 + pq;
    int pix = row * W_ + w;
    int p = b * HW_ + pix;

    const unsigned short* xb = xnb + (size_t)b * HW_ * 64;

    // ---- phase 1: conv27, depth-2 load pipeline ----
    f32x4 cacc[2];
    cacc[0] = f32x4{0.f, 0.f, 0.f, 0.f};
    cacc[1] = f32x4{0.f, 0.f, 0.f, 0.f};

    auto ldconv = [&](int s) -> ushortx8 {
        const int k = s >> 1;
        const int dy = k / 3 - 1, dx = k % 3 - 1;
        bool ok = ((unsigned)(h + dy) < (unsigned)H_) &&
                  ((unsigned)(w + dx) < (unsigned)W_);
        int sp = ok ? (pix + dy * W_ + dx) : pix;
        int cbase = (s & 1) * 32 + kchunk * 8;
        return ok ? *reinterpret_cast<const ushortx8*>(xb + (size_t)sp * 64 + cbase)
                  : ushortx8{0, 0, 0, 0, 0, 0, 0, 0};
    };

    ushortx8 cb0 = ldconv(0);
    ushortx8 cb1 = ldconv(1);
    #pragma unroll
    for (int s = 0; s < KSTEPS_; ++s) {
        ushortx8 cur = (s & 1) ? cb1 : cb0;
        if (s + 2 < KSTEPS_) {
            if (s & 1) cb1 = ldconv(s + 2); else cb0 = ldconv(s + 2);
        }
        bf16x8 bv = __builtin_bit_cast(bf16x8, cur);
        #pragma unroll
        for (int t = 0; t < 2; ++t) {
            bf16x8 afrag = *reinterpret_cast<const bf16x8*>(
                wpc + ((size_t)(t * KSTEPS_ + s) * 64 + lane) * 8);
            cacc[t] = __builtin_amdgcn_mfma_f32_16x16x32_bf16(afrag, bv, cacc[t], 0, 0, 0);
        }
    }

    // bias / sigmoid, transpose via LDS (single wave: barrier is cheap)
    #pragma unroll
    for (int t = 0; t < 2; ++t) {
        f32x4 sv;
        #pragma unroll
        for (int r = 0; r < 4; ++r) {
            int oc = t * 16 + kchunk * 4 + r;
            float a = cacc[t][r];
            if (oc < 18)      sv[r] = a + offb[oc];
            else if (oc < 27) sv[r] = 1.f / (1.f + expf(-(a + maskb[oc - 18])));
            else              sv[r] = 0.f;
        }
        *reinterpret_cast<f32x4*>(&som[pq][t * 16 + kchunk * 4]) = sv;
    }
    __syncthreads();

    float om[28];
    #pragma unroll
    for (int i = 0; i < 7; ++i) {
        f32x4 t4 = *reinterpret_cast<const f32x4*>(&som[pq][4 * i]);
        om[4 * i + 0] = t4[0]; om[4 * i + 1] = t4[1];
        om[4 * i + 2] = t4[2]; om[4 * i + 3] = t4[3];
    }

    // ---- phase 2: gather + contraction, 1-tap-ahead pipeline ----
    f32x4 acc[4];
    #pragma unroll
    for (int t = 0; t < 4; ++t) acc[t] = f32x4{0.f, 0.f, 0.f, 0.f};

    ushortx8 g0[8], g1[8];
    float    q0[4], q1[4];

    auto issue = [&](int k, ushortx8* g, float* q) {
        float dy = om[2 * k], dx = om[2 * k + 1], m = om[18 + k];
        float py = dy + (float)(h - 1 + k / 3);
        float px = dx + (float)(w - 1 + k % 3);
        float fy = floorf(py), fx = floorf(px);
        float ly = py - fy, lx = px - fx;
        int y0 = (int)fy, x0 = (int)fx;
        int y1 = y0 + 1, x1 = x0 + 1;
        bool oky0 = (unsigned)y0 < (unsigned)H_;
        bool oky1 = (unsigned)y1 < (unsigned)H_;
        bool okx0 = (unsigned)x0 < (unsigned)W_;
        bool okx1 = (unsigned)x1 < (unsigned)W_;
        int cy0 = min(max(y0, 0), H_ - 1), cy1 = min(max(y1, 0), H_ - 1);
        int cx0 = min(max(x0, 0), W_ - 1), cx1 = min(max(x1, 0), W_ - 1);
        int a00 = cy0 * W_ + cx0, a01 = cy0 * W_ + cx1;
        int a10 = cy1 * W_ + cx0, a11 = cy1 * W_ + cx1;
        q[0] = (oky0 && okx0) ? (1.f - ly) * (1.f - lx) * m : 0.f;
        q[1] = (oky0 && okx1) ? (1.f - ly) * lx * m : 0.f;
        q[2] = (oky1 && okx0) ? ly * (1.f - lx) * m : 0.f;
        q[3] = (oky1 && okx1) ? ly * lx * m : 0.f;
        int cb = kchunk * 8;
        g[0] = *reinterpret_cast<const ushortx8*>(xb + (size_t)a00 * 64 + cb);
        g[1] = *reinterpret_cast<const ushortx8*>(xb + (size_t)a01 * 64 + cb);
        g[2] = *reinterpret_cast<const ushortx8*>(xb + (size_t)a10 * 64 + cb);
        g[3] = *reinterpret_cast<const ushortx8*>(xb + (size_t)a11 * 64 + cb);
        g[4] = *reinterpret_cast<const ushortx8*>(xb + (size_t)a00 * 64 + cb + 32);
        g[5] = *reinterpret_cast<const ushortx8*>(xb + (size_t)a01 * 64 + cb + 32);
        g[6] = *reinterpret_cast<const ushortx8*>(xb + (size_t)a10 * 64 + cb + 32);
        g[7] = *reinterpret_cast<const ushortx8*>(xb + (size_t)a11 * 64 + cb + 32);
    };

    issue(0, g0, q0);
    #pragma unroll
    for (int k = 0; k < KK_; ++k) {
        ushortx8* gc = (k & 1) ? g1 : g0;
        float*    qc = (k & 1) ? q1 : q0;
        if (k + 1 < KK_) {
            if (k & 1) issue(k + 1, g0, q0); else issue(k + 1, g1, q1);
        }
        #pragma unroll
        for (int half = 0; half < 2; ++half) {
            int s = k * 2 + half;
            union { unsigned short u[8]; bf16x8 v; } bu;
            #pragma unroll
            for (int j = 0; j < 8; ++j) {
                float v = qc[0] * bf2f(gc[half * 4 + 0][j])
                        + qc[1] * bf2f(gc[half * 4 + 1][j])
                        + qc[2] * bf2f(gc[half * 4 + 2][j])
                        + qc[3] * bf2f(gc[half * 4 + 3][j]);
                bu.u[j] = f2bf(v);
            }
            #pragma unroll
            for (int t = 0; t < 4; ++t) {
                bf16x8 afrag = *reinterpret_cast<const bf16x8*>(
                    wpack + ((size_t)(t * KSTEPS_ + s) * 64 + lane) * 8);
                acc[t] = __builtin_amdgcn_mfma_f32_16x16x32_bf16(afrag, bu.v, acc[t], 0, 0, 0);
            }
        }
    }

    unsigned short* zb = xdefb + (size_t)p * 64;
    #pragma unroll
    for (int t = 0; t < 4; ++t) {
        ushortx4 st;
        #pragma unroll
        for (int r = 0; r < 4; ++r) {
            int oc = t * 16 + kchunk * 4 + r;
            st[r] = f2bf(acc[t][r] + db[oc]);
        }
        *reinterpret_cast<ushortx4*>(zb + t * 16 + kchunk * 4) = st;
    }
}

// ---------------- fusion conv via MFMA + pre_mask blend --------------------
__global__ void __launch_bounds__(64) fuse_mfma(
        const unsigned short* __restrict__ xdefb,  // NHWC
        const unsigned short* __restrict__ wpf,
        const float* __restrict__ fb,
        const float* __restrict__ premask,
        const float* __restrict__ xin,             // NCHW
        float* __restrict__ out) {                 // NCHW
    int lane = threadIdx.x;
    int bid  = blockIdx.x;
    int row  = bid % H_;
    int rest = bid / H_;
    int tx   = rest % TX_;
    int b    = rest / TX_;
    int pq = lane & 15;
    int kchunk = lane >> 4;
    int h = row, w = tx * 16 + pq;
    int pix = row * W_ + w;
    int p = b * HW_ + pix;

    f32x4 acc[4];
    #pragma unroll
    for (int t = 0; t < 4; ++t) acc[t] = f32x4{0.f, 0.f, 0.f, 0.f};

    const unsigned short* xb = xdefb + (size_t)b * HW_ * 64;

    auto ldf = [&](int s) -> ushortx8 {
        const int k = s >> 1;
        const int dy = k / 3 - 1, dx = k % 3 - 1;
        bool ok = ((unsigned)(h + dy) < (unsigned)H_) &&
                  ((unsigned)(w + dx) < (unsigned)W_);
        int sp = ok ? (pix + dy * W_ + dx) : pix;
        int cbase = (s & 1) * 32 + kchunk * 8;
        return ok ? *reinterpret_cast<const ushortx8*>(xb + (size_t)sp * 64 + cbase)
                  : ushortx8{0, 0, 0, 0, 0, 0, 0, 0};
    };

    ushortx8 cb0 = ldf(0);
    ushortx8 cb1 = ldf(1);
    #pragma unroll
    for (int s = 0; s < KSTEPS_; ++s) {
        ushortx8 cur = (s & 1) ? cb1 : cb0;
        if (s + 2 < KSTEPS_) {
            if (s & 1) cb1 = ldf(s + 2); else cb0 = ldf(s + 2);
        }
        bf16x8 bv = __builtin_bit_cast(bf16x8, cur);
        #pragma unroll
        for (int t = 0; t < 4; ++t) {
            bf16x8 afrag = *reinterpret_cast<const bf16x8*>(
                wpf + ((size_t)(t * KSTEPS_ + s) * 64 + lane) * 8);
            acc[t] = __builtin_amdgcn_mfma_f32_16x16x32_bf16(afrag, bv, acc[t], 0, 0, 0);
        }
    }

    float pm = premask[(size_t)b * HW_ + pix];
    #pragma unroll
    for (int t = 0; t < 4; ++t) {
        #pragma unroll
        for (int r = 0; r < 4; ++r) {
            int oc = t * 16 + kchunk * 4 + r;
            size_t oidx = ((size_t)b * C_ + oc) * HW_ + pix;
            out[oidx] = (acc[t][r] + fb[oc]) * pm + xin[oidx] * (1.f - pm);
        }
    }
}

extern "C" void kernel_launch(void* const* d_in, const int* in_sizes, int n_in,
                              void* d_out, int out_size, void* d_ws, size_t ws_size,
                              hipStream_t stream) {
    const float* x       = (const float*)d_in[0];
    const float* premask = (const float*)d_in[1];
    const float* lnw     = (const float*)d_in[2];
    const float* lnb     = (const float*)d_in[3];
    const float* offw    = (const float*)d_in[4];
    const float* offb    = (const float*)d_in[5];
    const float* maskw   = (const float*)d_in[6];
    const float* maskb   = (const float*)d_in[7];
    const float* dw      = (const float*)d_in[8];
    const float* db      = (const float*)d_in[9];
    const float* fw      = (const float*)d_in[10];
    const float* fb      = (const float*)d_in[11];
    float* out = (float*)d_out;

    char* ws = (char*)d_ws;
    unsigned short* xnb   = (unsigned short*)ws;  ws += sizeof(short) * (size_t)BHW_ * 64;
    unsigned short* xdefb = (unsigned short*)ws;  ws += sizeof(short) * (size_t)BHW_ * 64;
    unsigned short* wpack = (unsigned short*)ws;  ws += sizeof(short) * 4 * KSTEPS_ * 64 * 8;
    unsigned short* wpf   = (unsigned short*)ws;  ws += sizeof(short) * 4 * KSTEPS_ * 64 * 8;
    unsigned short* wpc   = (unsigned short*)ws;  ws += sizeof(short) * 2 * KSTEPS_ * 64 * 8;

    const int grid2d = B_ * TX_ * H_;   // 4608 one-wave blocks

    ln_kernel<<<(BHW_ + 255) / 256, 256, 0, stream>>>(x, lnw, lnb, xnb);
    prepack_kernel<<<36, 256, 0, stream>>>(dw, fw, offw, maskw, wpack, wpf, wpc);
    dc_mfma<<<grid2d, 64, 0, stream>>>(
        xnb, wpc, offb, maskb, wpack, db, xdefb);
    fuse_mfma<<<grid2d, 64, 0, stream>>>(xdefb, wpf, fb, premask, x, out);
}

// Round 10
// 105.382 us; speedup vs baseline: 1.2653x; 1.2653x over previous
//
#include <hip/hip_runtime.h>
#include <hip/hip_bf16.h>
#include <math.h>

#define B_ 2
#define C_ 64
#define H_ 192
#define W_ 192
#define HW_ (H_*W_)
#define BHW_ (B_*HW_)
#define KK_ 9
#define CK_ (C_*KK_)      // 576
#define KSTEPS_ (CK_/32)  // 18
#define TX_ 12            // W_/16 column tiles
#define WROWS_ 5          // staged window rows  (h-2 .. h+2)
#define WCOLS_ 21         // staged window cols  (w0-2 .. w0+18)
#define WCHUNKS_ (WROWS_*WCOLS_*8)   // 840 16B-chunks

typedef __bf16 bf16x8 __attribute__((ext_vector_type(8)));
typedef float  f32x4  __attribute__((ext_vector_type(4)));
typedef unsigned short ushortx8 __attribute__((ext_vector_type(8)));
typedef unsigned short ushortx4 __attribute__((ext_vector_type(4)));

__device__ __forceinline__ float bf2f(unsigned short u) {
    unsigned int t = ((unsigned int)u) << 16;
    return __builtin_bit_cast(float, t);
}
__device__ __forceinline__ unsigned short f2bf(float f) {
    __hip_bfloat16 hb = __float2bfloat16(f);
    return *reinterpret_cast<unsigned short*>(&hb);
}

// ---------------- LayerNorm over channel axis -> bf16 NHWC ------------------
__global__ void ln_kernel(const float* __restrict__ x,
                          const float* __restrict__ lnw,
                          const float* __restrict__ lnb,
                          unsigned short* __restrict__ xnb) {   // [BHW][64]
    int p = blockIdx.x * blockDim.x + threadIdx.x;
    if (p >= BHW_) return;
    int b = p / HW_, pix = p % HW_;
    const float* xb = x + (size_t)b * C_ * HW_ + pix;
    float v[C_];
    float s = 0.f, s2 = 0.f;
    #pragma unroll
    for (int c = 0; c < C_; ++c) {
        v[c] = xb[(size_t)c * HW_];
        s += v[c]; s2 += v[c] * v[c];
    }
    float mu  = s * (1.0f / C_);
    float var = s2 * (1.0f / C_) - mu * mu;
    float inv = rsqrtf(var + 1e-5f);
    unsigned short* zb = xnb + (size_t)p * 64;
    #pragma unroll
    for (int g = 0; g < 8; ++g) {
        ushortx8 st;
        #pragma unroll
        for (int j = 0; j < 8; ++j) {
            int c = g * 8 + j;
            st[j] = f2bf((v[c] - mu) * inv * lnw[c] + lnb[c]);
        }
        *reinterpret_cast<ushortx8*>(zb + g * 8) = st;
    }
}

// ---------------- weight prepack (tap-outer ck = k*64+c) -------------------
__global__ void prepack_kernel(const float* __restrict__ dw,
                               const float* __restrict__ fw,
                               const float* __restrict__ offw,
                               const float* __restrict__ maskw,
                               unsigned short* __restrict__ wpack,
                               unsigned short* __restrict__ wpf,
                               unsigned short* __restrict__ wpc) {
    const int n1 = 4 * KSTEPS_ * 64 * 8;   // deform
    const int n2 = 4 * KSTEPS_ * 64 * 8;   // fusion
    const int n3 = 2 * KSTEPS_ * 64 * 8;   // conv27
    int gid = blockIdx.x * blockDim.x + threadIdx.x;
    int nth = gridDim.x * blockDim.x;
    for (int idx = gid; idx < n1 + n2 + n3; idx += nth) {
        int which = (idx < n1) ? 0 : (idx < n1 + n2 ? 1 : 2);
        int rem = idx - (which == 0 ? 0 : (which == 1 ? n1 : n1 + n2));
        int j = rem & 7;
        int l = (rem >> 3) & 63;
        int rest = rem >> 9;
        int s = rest % KSTEPS_;
        int t = rest / KSTEPS_;
        int oc = t * 16 + (l & 15);
        int ck = s * 32 + (l >> 4) * 8 + j;
        int k = ck >> 6, c = ck & 63;
        float v;
        if (which == 0) {
            v = dw[(size_t)oc * CK_ + c * 9 + k];
        } else if (which == 1) {
            v = fw[(size_t)oc * CK_ + c * 9 + k];
        } else {
            v = (oc < 18) ? offw[(size_t)oc * CK_ + c * 9 + k]
              : (oc < 27) ? maskw[(size_t)(oc - 18) * CK_ + c * 9 + k]
              : 0.f;
        }
        unsigned short u = f2bf(v);
        if (which == 0) wpack[rem] = u;
        else if (which == 1) wpf[rem] = u;
        else wpc[rem] = u;
    }
}

// ---------------- merged: conv27 + deformable conv, LDS-windowed -----------
// 1-wave block = 16x1 row segment. Window rows h-2..h+2, cols w0-2..w0+18
// staged to LDS with seg^(col&7) swizzle. Conv B-loads and bilinear corners
// read LDS; rare out-of-window corners fall back to global.
__global__ void __launch_bounds__(64) dc_mfma(
        const unsigned short* __restrict__ xnb,   // NHWC
        const unsigned short* __restrict__ wpc,
        const float* __restrict__ offb, const float* __restrict__ maskb,
        const unsigned short* __restrict__ wpack,
        const float* __restrict__ db,
        unsigned short* __restrict__ xdefb) {     // NHWC
    __shared__ ushortx8 win[WCHUNKS_];   // 13440 B
    __shared__ float som[16][36];        // 2304 B
    int lane = threadIdx.x;
    int bid  = blockIdx.x;
    int row  = bid % H_;
    int rest = bid / H_;            // b*TX_ + tx
    int tx   = rest % TX_;
    int b    = rest / TX_;
    int pq = lane & 15;
    int kchunk = lane >> 4;
    int h = row, w0 = tx * 16, w = w0 + pq;
    int pix = row * W_ + w;
    int p = b * HW_ + pix;

    const unsigned short* xb = xnb + (size_t)b * HW_ * 64;

    // ---- stage window (coalesced, one-touch, swizzled) ----
    #pragma unroll
    for (int i = 0; i < 14; ++i) {
        int idx = i * 64 + lane;
        if (idx < WCHUNKS_) {
            int r   = idx / (WCOLS_ * 8);
            int rem2 = idx - r * (WCOLS_ * 8);
            int c   = rem2 >> 3;
            int seg = rem2 & 7;
            int gy = min(max(h - 2 + r, 0), H_ - 1);
            int gx = min(max(w0 - 2 + c, 0), W_ - 1);
            ushortx8 v = *reinterpret_cast<const ushortx8*>(
                xb + ((size_t)(gy * W_ + gx) * 64 + seg * 8));
            win[(r * WCOLS_ + c) * 8 + (seg ^ (c & 7))] = v;
        }
    }
    __syncthreads();

    // ---- phase 1: conv27, B from LDS ----
    f32x4 cacc[2];
    cacc[0] = f32x4{0.f, 0.f, 0.f, 0.f};
    cacc[1] = f32x4{0.f, 0.f, 0.f, 0.f};

    #pragma unroll
    for (int s = 0; s < KSTEPS_; ++s) {
        const int k = s >> 1;
        const int dy = k / 3 - 1, dx = k % 3 - 1;
        bool ok = ((unsigned)(h + dy) < (unsigned)H_) &&
                  ((unsigned)(w + dx) < (unsigned)W_);
        int wr = dy + 2;                 // 1..3
        int wc = pq + dx + 2;            // 1..18
        int seg = (s & 1) * 4 + kchunk;
        ushortx8 u = win[(wr * WCOLS_ + wc) * 8 + (seg ^ (wc & 7))];
        if (!ok) u = ushortx8{0, 0, 0, 0, 0, 0, 0, 0};
        bf16x8 bv = __builtin_bit_cast(bf16x8, u);
        #pragma unroll
        for (int t = 0; t < 2; ++t) {
            bf16x8 afrag = *reinterpret_cast<const bf16x8*>(
                wpc + ((size_t)(t * KSTEPS_ + s) * 64 + lane) * 8);
            cacc[t] = __builtin_amdgcn_mfma_f32_16x16x32_bf16(afrag, bv, cacc[t], 0, 0, 0);
        }
    }

    // bias / sigmoid, transpose via LDS
    #pragma unroll
    for (int t = 0; t < 2; ++t) {
        f32x4 sv;
        #pragma unroll
        for (int r = 0; r < 4; ++r) {
            int oc = t * 16 + kchunk * 4 + r;
            float a = cacc[t][r];
            if (oc < 18)      sv[r] = a + offb[oc];
            else if (oc < 27) sv[r] = 1.f / (1.f + expf(-(a + maskb[oc - 18])));
            else              sv[r] = 0.f;
        }
        *reinterpret_cast<f32x4*>(&som[pq][t * 16 + kchunk * 4]) = sv;
    }
    __syncthreads();

    float om[28];
    #pragma unroll
    for (int i = 0; i < 7; ++i) {
        f32x4 t4 = *reinterpret_cast<const f32x4*>(&som[pq][4 * i]);
        om[4 * i + 0] = t4[0]; om[4 * i + 1] = t4[1];
        om[4 * i + 2] = t4[2]; om[4 * i + 3] = t4[3];
    }

    // ---- phase 2: bilinear gather from LDS + MFMA contraction ----
    f32x4 acc[4];
    #pragma unroll
    for (int t = 0; t < 4; ++t) acc[t] = f32x4{0.f, 0.f, 0.f, 0.f};

    #pragma unroll
    for (int k = 0; k < KK_; ++k) {
        float dy = om[2 * k], dx = om[2 * k + 1], m = om[18 + k];
        float py = dy + (float)(h - 1 + k / 3);
        float px = dx + (float)(w - 1 + k % 3);
        float fy = floorf(py), fx = floorf(px);
        float ly = py - fy, lx = px - fx;
        int y0 = (int)fy, x0 = (int)fx;
        int y1 = y0 + 1, x1 = x0 + 1;
        bool oky0 = (unsigned)y0 < (unsigned)H_;
        bool oky1 = (unsigned)y1 < (unsigned)H_;
        bool okx0 = (unsigned)x0 < (unsigned)W_;
        bool okx1 = (unsigned)x1 < (unsigned)W_;
        float q00 = (oky0 && okx0) ? (1.f - ly) * (1.f - lx) * m : 0.f;
        float q01 = (oky0 && okx1) ? (1.f - ly) * lx * m : 0.f;
        float q10 = (oky1 && okx0) ? ly * (1.f - lx) * m : 0.f;
        float q11 = (oky1 && okx1) ? ly * lx * m : 0.f;

        // window coords
        int wr0 = y0 - (h - 2), wr1 = y1 - (h - 2);
        int wc0 = x0 - (w0 - 2), wc1 = x1 - (w0 - 2);
        bool inr0 = (unsigned)wr0 < (unsigned)WROWS_;
        bool inr1 = (unsigned)wr1 < (unsigned)WROWS_;
        bool inc0 = (unsigned)wc0 < (unsigned)WCOLS_;
        bool inc1 = (unsigned)wc1 < (unsigned)WCOLS_;
        bool in00 = inr0 && inc0, in01 = inr0 && inc1;
        bool in10 = inr1 && inc0, in11 = inr1 && inc1;
        int swr0 = min(max(wr0, 0), WROWS_ - 1), swr1 = min(max(wr1, 0), WROWS_ - 1);
        int swc0 = min(max(wc0, 0), WCOLS_ - 1), swc1 = min(max(wc1, 0), WCOLS_ - 1);
        int cb00 = (swr0 * WCOLS_ + swc0) * 8, sx00 = swc0 & 7;
        int cb01 = (swr0 * WCOLS_ + swc1) * 8, sx01 = swc1 & 7;
        int cb10 = (swr1 * WCOLS_ + swc0) * 8, sx10 = swc0 & 7;
        int cb11 = (swr1 * WCOLS_ + swc1) * 8, sx11 = swc1 & 7;
        // clamped global coords (only used on fallback; q!=0 implies in-image)
        int cy0 = min(max(y0, 0), H_ - 1), cy1 = min(max(y1, 0), H_ - 1);
        int cx0 = min(max(x0, 0), W_ - 1), cx1 = min(max(x1, 0), W_ - 1);

        #pragma unroll
        for (int half = 0; half < 2; ++half) {
            int s = k * 2 + half;
            int seg = half * 4 + kchunk;
            int cbg = half * 32 + kchunk * 8;
            ushortx8 v00 = win[cb00 + (seg ^ sx00)];
            ushortx8 v01 = win[cb01 + (seg ^ sx01)];
            ushortx8 v10 = win[cb10 + (seg ^ sx10)];
            ushortx8 v11 = win[cb11 + (seg ^ sx11)];
            if (q00 != 0.f && !in00)
                v00 = *reinterpret_cast<const ushortx8*>(xb + ((size_t)(cy0 * W_ + cx0) * 64 + cbg));
            if (q01 != 0.f && !in01)
                v01 = *reinterpret_cast<const ushortx8*>(xb + ((size_t)(cy0 * W_ + cx1) * 64 + cbg));
            if (q10 != 0.f && !in10)
                v10 = *reinterpret_cast<const ushortx8*>(xb + ((size_t)(cy1 * W_ + cx0) * 64 + cbg));
            if (q11 != 0.f && !in11)
                v11 = *reinterpret_cast<const ushortx8*>(xb + ((size_t)(cy1 * W_ + cx1) * 64 + cbg));
            union { unsigned short u[8]; bf16x8 v; } bu;
            #pragma unroll
            for (int j = 0; j < 8; ++j) {
                float v = q00 * bf2f(v00[j]) + q01 * bf2f(v01[j])
                        + q10 * bf2f(v10[j]) + q11 * bf2f(v11[j]);
                bu.u[j] = f2bf(v);
            }
            #pragma unroll
            for (int t = 0; t < 4; ++t) {
                bf16x8 afrag = *reinterpret_cast<const bf16x8*>(
                    wpack + ((size_t)(t * KSTEPS_ + s) * 64 + lane) * 8);
                acc[t] = __builtin_amdgcn_mfma_f32_16x16x32_bf16(afrag, bu.v, acc[t], 0, 0, 0);
            }
        }
    }

    unsigned short* zb = xdefb + (size_t)p * 64;
    #pragma unroll
    for (int t = 0; t < 4; ++t) {
        ushortx4 st;
        #pragma unroll
        for (int r = 0; r < 4; ++r) {
            int oc = t * 16 + kchunk * 4 + r;
            st[r] = f2bf(acc[t][r] + db[oc]);
        }
        *reinterpret_cast<ushortx4*>(zb + t * 16 + kchunk * 4) = st;
    }
}

// ---------------- fusion conv via MFMA + pre_mask blend --------------------
__global__ void __launch_bounds__(64) fuse_mfma(
        const unsigned short* __restrict__ xdefb,  // NHWC
        const unsigned short* __restrict__ wpf,
        const float* __restrict__ fb,
        const float* __restrict__ premask,
        const float* __restrict__ xin,             // NCHW
        float* __restrict__ out) {                 // NCHW
    int lane = threadIdx.x;
    int bid  = blockIdx.x;
    int row  = bid % H_;
    int rest = bid / H_;
    int tx   = rest % TX_;
    int b    = rest / TX_;
    int pq = lane & 15;
    int kchunk = lane >> 4;
    int h = row, w = tx * 16 + pq;
    int pix = row * W_ + w;
    int p = b * HW_ + pix;

    f32x4 acc[4];
    #pragma unroll
    for (int t = 0; t < 4; ++t) acc[t] = f32x4{0.f, 0.f, 0.f, 0.f};

    const unsigned short* xb = xdefb + (size_t)b * HW_ * 64;

    auto ldf = [&](int s) -> ushortx8 {
        const int k = s >> 1;
        const int dy = k / 3 - 1, dx = k % 3 - 1;
        bool ok = ((unsigned)(h + dy) < (unsigned)H_) &&
                  ((unsigned)(w + dx) < (unsigned)W_);
        int sp = ok ? (pix + dy * W_ + dx) : pix;
        int cbase = (s & 1) * 32 + kchunk * 8;
        return ok ? *reinterpret_cast<const ushortx8*>(xb + (size_t)sp * 64 + cbase)
                  : ushortx8{0, 0, 0, 0, 0, 0, 0, 0};
    };

    ushortx8 cb0 = ldf(0);
    ushortx8 cb1 = ldf(1);
    #pragma unroll
    for (int s = 0; s < KSTEPS_; ++s) {
        ushortx8 cur = (s & 1) ? cb1 : cb0;
        if (s + 2 < KSTEPS_) {
            if (s & 1) cb1 = ldf(s + 2); else cb0 = ldf(s + 2);
        }
        bf16x8 bv = __builtin_bit_cast(bf16x8, cur);
        #pragma unroll
        for (int t = 0; t < 4; ++t) {
            bf16x8 afrag = *reinterpret_cast<const bf16x8*>(
                wpf + ((size_t)(t * KSTEPS_ + s) * 64 + lane) * 8);
            acc[t] = __builtin_amdgcn_mfma_f32_16x16x32_bf16(afrag, bv, acc[t], 0, 0, 0);
        }
    }

    float pm = premask[(size_t)b * HW_ + pix];
    #pragma unroll
    for (int t = 0; t < 4; ++t) {
        #pragma unroll
        for (int r = 0; r < 4; ++r) {
            int oc = t * 16 + kchunk * 4 + r;
            size_t oidx = ((size_t)b * C_ + oc) * HW_ + pix;
            out[oidx] = (acc[t][r] + fb[oc]) * pm + xin[oidx] * (1.f - pm);
        }
    }
}

extern "C" void kernel_launch(void* const* d_in, const int* in_sizes, int n_in,
                              void* d_out, int out_size, void* d_ws, size_t ws_size,
                              hipStream_t stream) {
    const float* x       = (const float*)d_in[0];
    const float* premask = (const float*)d_in[1];
    const float* lnw     = (const float*)d_in[2];
    const float* lnb     = (const float*)d_in[3];
    const float* offw    = (const float*)d_in[4];
    const float* offb    = (const float*)d_in[5];
    const float* maskw   = (const float*)d_in[6];
    const float* maskb   = (const float*)d_in[7];
    const float* dw      = (const float*)d_in[8];
    const float* db      = (const float*)d_in[9];
    const float* fw      = (const float*)d_in[10];
    const float* fb      = (const float*)d_in[11];
    float* out = (float*)d_out;

    char* ws = (char*)d_ws;
    unsigned short* xnb   = (unsigned short*)ws;  ws += sizeof(short) * (size_t)BHW_ * 64;
    unsigned short* xdefb = (unsigned short*)ws;  ws += sizeof(short) * (size_t)BHW_ * 64;
    unsigned short* wpack = (unsigned short*)ws;  ws += sizeof(short) * 4 * KSTEPS_ * 64 * 8;
    unsigned short* wpf   = (unsigned short*)ws;  ws += sizeof(short) * 4 * KSTEPS_ * 64 * 8;
    unsigned short* wpc   = (unsigned short*)ws;  ws += sizeof(short) * 2 * KSTEPS_ * 64 * 8;

    const int grid2d = B_ * TX_ * H_;   // 4608 one-wave blocks

    ln_kernel<<<(BHW_ + 255) / 256, 256, 0, stream>>>(x, lnw, lnb, xnb);
    prepack_kernel<<<36, 256, 0, stream>>>(dw, fw, offw, maskw, wpack, wpf, wpc);
    dc_mfma<<<grid2d, 64, 0, stream>>>(
        xnb, wpc, offb, maskb, wpack, db, xdefb);
    fuse_mfma<<<grid2d, 64, 0, stream>>>(xdefb, wpf, fb, premask, x, out);
}

// Round 11
// 99.133 us; speedup vs baseline: 1.3451x; 1.0630x over previous
//
#include <hip/hip_runtime.h>
#include <hip/hip_bf16.h>
#include <math.h>

#define B_ 2
#define C_ 64
#define H_ 192
#define W_ 192
#define HW_ (H_*W_)
#define BHW_ (B_*HW_)
#define KK_ 9
#define CK_ (C_*KK_)      // 576
#define KSTEPS_ (CK_/32)  // 18
#define TX_ 12            // W_/16 column tiles
#define RG_ 4             // rows per block (one per wave)
#define WROWS_ 8          // staged window rows  (h0-2 .. h0+5)
#define WCOLS_ 21         // staged window cols  (w0-2 .. w0+18)
#define WCHUNKS_ (WROWS_*WCOLS_*8)   // 1344 16B-chunks

typedef __bf16 bf16x8 __attribute__((ext_vector_type(8)));
typedef float  f32x4  __attribute__((ext_vector_type(4)));
typedef unsigned short ushortx8 __attribute__((ext_vector_type(8)));
typedef unsigned short ushortx4 __attribute__((ext_vector_type(4)));

__device__ __forceinline__ float bf2f(unsigned short u) {
    unsigned int t = ((unsigned int)u) << 16;
    return __builtin_bit_cast(float, t);
}
__device__ __forceinline__ unsigned short f2bf(float f) {
    __hip_bfloat16 hb = __float2bfloat16(f);
    return *reinterpret_cast<unsigned short*>(&hb);
}

// ---------------- LayerNorm over channel axis -> bf16 NHWC ------------------
__global__ void ln_kernel(const float* __restrict__ x,
                          const float* __restrict__ lnw,
                          const float* __restrict__ lnb,
                          unsigned short* __restrict__ xnb) {   // [BHW][64]
    int p = blockIdx.x * blockDim.x + threadIdx.x;
    if (p >= BHW_) return;
    int b = p / HW_, pix = p % HW_;
    const float* xb = x + (size_t)b * C_ * HW_ + pix;
    float v[C_];
    float s = 0.f, s2 = 0.f;
    #pragma unroll
    for (int c = 0; c < C_; ++c) {
        v[c] = xb[(size_t)c * HW_];
        s += v[c]; s2 += v[c] * v[c];
    }
    float mu  = s * (1.0f / C_);
    float var = s2 * (1.0f / C_) - mu * mu;
    float inv = rsqrtf(var + 1e-5f);
    unsigned short* zb = xnb + (size_t)p * 64;
    #pragma unroll
    for (int g = 0; g < 8; ++g) {
        ushortx8 st;
        #pragma unroll
        for (int j = 0; j < 8; ++j) {
            int c = g * 8 + j;
            st[j] = f2bf((v[c] - mu) * inv * lnw[c] + lnb[c]);
        }
        *reinterpret_cast<ushortx8*>(zb + g * 8) = st;
    }
}

// ---------------- weight prepack (tap-outer ck = k*64+c) -------------------
__global__ void prepack_kernel(const float* __restrict__ dw,
                               const float* __restrict__ fw,
                               const float* __restrict__ offw,
                               const float* __restrict__ maskw,
                               unsigned short* __restrict__ wpack,
                               unsigned short* __restrict__ wpf,
                               unsigned short* __restrict__ wpc) {
    const int n1 = 4 * KSTEPS_ * 64 * 8;   // deform
    const int n2 = 4 * KSTEPS_ * 64 * 8;   // fusion
    const int n3 = 2 * KSTEPS_ * 64 * 8;   // conv27
    int gid = blockIdx.x * blockDim.x + threadIdx.x;
    int nth = gridDim.x * blockDim.x;
    for (int idx = gid; idx < n1 + n2 + n3; idx += nth) {
        int which = (idx < n1) ? 0 : (idx < n1 + n2 ? 1 : 2);
        int rem = idx - (which == 0 ? 0 : (which == 1 ? n1 : n1 + n2));
        int j = rem & 7;
        int l = (rem >> 3) & 63;
        int rest = rem >> 9;
        int s = rest % KSTEPS_;
        int t = rest / KSTEPS_;
        int oc = t * 16 + (l & 15);
        int ck = s * 32 + (l >> 4) * 8 + j;
        int k = ck >> 6, c = ck & 63;
        float v;
        if (which == 0) {
            v = dw[(size_t)oc * CK_ + c * 9 + k];
        } else if (which == 1) {
            v = fw[(size_t)oc * CK_ + c * 9 + k];
        } else {
            v = (oc < 18) ? offw[(size_t)oc * CK_ + c * 9 + k]
              : (oc < 27) ? maskw[(size_t)(oc - 18) * CK_ + c * 9 + k]
              : 0.f;
        }
        unsigned short u = f2bf(v);
        if (which == 0) wpack[rem] = u;
        else if (which == 1) wpf[rem] = u;
        else wpc[rem] = u;
    }
}

// ---------------- merged: conv27 + deformable conv, shared LDS window ------
// 256-thread block = 4 rows (one wave per row) sharing one staged window:
// rows h0-2..h0+5, cols w0-2..w0+18, seg^(col&7) swizzle.
__global__ void __launch_bounds__(256) dc_mfma(
        const unsigned short* __restrict__ xnb,   // NHWC
        const unsigned short* __restrict__ wpc,
        const float* __restrict__ offb, const float* __restrict__ maskb,
        const unsigned short* __restrict__ wpack,
        const float* __restrict__ db,
        unsigned short* __restrict__ xdefb) {     // NHWC
    __shared__ ushortx8 win[WCHUNKS_];    // 21504 B
    __shared__ float som[RG_][16][36];    // 9216 B
    int tid  = threadIdx.x;
    int wave = tid >> 6;
    int lane = tid & 63;
    int bid  = blockIdx.x;
    int rg   = bid % (H_ / RG_);
    int rest = bid / (H_ / RG_);    // b*TX_ + tx
    int tx   = rest % TX_;
    int b    = rest / TX_;
    int pq = lane & 15;
    int kchunk = lane >> 4;
    int h0 = rg * RG_;
    int h = h0 + wave, w0 = tx * 16, w = w0 + pq;
    int pix = h * W_ + w;
    int p = b * HW_ + pix;

    const unsigned short* xb = xnb + (size_t)b * HW_ * 64;

    // ---- stage shared window (coalesced, one-touch, swizzled) ----
    #pragma unroll
    for (int i = 0; i < 6; ++i) {
        int idx = i * 256 + tid;
        if (idx < WCHUNKS_) {
            int r    = idx / (WCOLS_ * 8);
            int rem2 = idx - r * (WCOLS_ * 8);
            int c    = rem2 >> 3;
            int seg  = rem2 & 7;
            int gy = min(max(h0 - 2 + r, 0), H_ - 1);
            int gx = min(max(w0 - 2 + c, 0), W_ - 1);
            ushortx8 v = *reinterpret_cast<const ushortx8*>(
                xb + ((size_t)(gy * W_ + gx) * 64 + seg * 8));
            win[(r * WCOLS_ + c) * 8 + (seg ^ (c & 7))] = v;
        }
    }
    __syncthreads();

    // ---- phase 1: conv27, B from LDS ----
    f32x4 cacc[2];
    cacc[0] = f32x4{0.f, 0.f, 0.f, 0.f};
    cacc[1] = f32x4{0.f, 0.f, 0.f, 0.f};

    #pragma unroll
    for (int s = 0; s < KSTEPS_; ++s) {
        const int k = s >> 1;
        const int dy = k / 3 - 1, dx = k % 3 - 1;
        bool ok = ((unsigned)(h + dy) < (unsigned)H_) &&
                  ((unsigned)(w + dx) < (unsigned)W_);
        int wr = wave + dy + 2;          // window row
        int wc = pq + dx + 2;            // window col
        int seg = (s & 1) * 4 + kchunk;
        ushortx8 u = win[(wr * WCOLS_ + wc) * 8 + (seg ^ (wc & 7))];
        if (!ok) u = ushortx8{0, 0, 0, 0, 0, 0, 0, 0};
        bf16x8 bv = __builtin_bit_cast(bf16x8, u);
        #pragma unroll
        for (int t = 0; t < 2; ++t) {
            bf16x8 afrag = *reinterpret_cast<const bf16x8*>(
                wpc + ((size_t)(t * KSTEPS_ + s) * 64 + lane) * 8);
            cacc[t] = __builtin_amdgcn_mfma_f32_16x16x32_bf16(afrag, bv, cacc[t], 0, 0, 0);
        }
    }

    // bias / sigmoid, per-wave transpose via private som slice
    #pragma unroll
    for (int t = 0; t < 2; ++t) {
        f32x4 sv;
        #pragma unroll
        for (int r = 0; r < 4; ++r) {
            int oc = t * 16 + kchunk * 4 + r;
            float a = cacc[t][r];
            if (oc < 18)      sv[r] = a + offb[oc];
            else if (oc < 27) sv[r] = 1.f / (1.f + expf(-(a + maskb[oc - 18])));
            else              sv[r] = 0.f;
        }
        *reinterpret_cast<f32x4*>(&som[wave][pq][t * 16 + kchunk * 4]) = sv;
    }
    // wave-private LDS region: program-order lgkmcnt wait suffices, no barrier

    float om[28];
    #pragma unroll
    for (int i = 0; i < 7; ++i) {
        f32x4 t4 = *reinterpret_cast<const f32x4*>(&som[wave][pq][4 * i]);
        om[4 * i + 0] = t4[0]; om[4 * i + 1] = t4[1];
        om[4 * i + 2] = t4[2]; om[4 * i + 3] = t4[3];
    }

    // ---- phase 2: bilinear gather from LDS + MFMA contraction ----
    f32x4 acc[4];
    #pragma unroll
    for (int t = 0; t < 4; ++t) acc[t] = f32x4{0.f, 0.f, 0.f, 0.f};

    #pragma unroll
    for (int k = 0; k < KK_; ++k) {
        float dy = om[2 * k], dx = om[2 * k + 1], m = om[18 + k];
        float py = dy + (float)(h - 1 + k / 3);
        float px = dx + (float)(w - 1 + k % 3);
        float fy = floorf(py), fx = floorf(px);
        float ly = py - fy, lx = px - fx;
        int y0 = (int)fy, x0 = (int)fx;
        int y1 = y0 + 1, x1 = x0 + 1;
        bool oky0 = (unsigned)y0 < (unsigned)H_;
        bool oky1 = (unsigned)y1 < (unsigned)H_;
        bool okx0 = (unsigned)x0 < (unsigned)W_;
        bool okx1 = (unsigned)x1 < (unsigned)W_;
        float q00 = (oky0 && okx0) ? (1.f - ly) * (1.f - lx) * m : 0.f;
        float q01 = (oky0 && okx1) ? (1.f - ly) * lx * m : 0.f;
        float q10 = (oky1 && okx0) ? ly * (1.f - lx) * m : 0.f;
        float q11 = (oky1 && okx1) ? ly * lx * m : 0.f;

        // window coords (origin h0-2, w0-2)
        int wr0 = y0 - (h0 - 2), wr1 = y1 - (h0 - 2);
        int wc0 = x0 - (w0 - 2), wc1 = x1 - (w0 - 2);
        bool inr0 = (unsigned)wr0 < (unsigned)WROWS_;
        bool inr1 = (unsigned)wr1 < (unsigned)WROWS_;
        bool inc0 = (unsigned)wc0 < (unsigned)WCOLS_;
        bool inc1 = (unsigned)wc1 < (unsigned)WCOLS_;
        bool in00 = inr0 && inc0, in01 = inr0 && inc1;
        bool in10 = inr1 && inc0, in11 = inr1 && inc1;
        int swr0 = min(max(wr0, 0), WROWS_ - 1), swr1 = min(max(wr1, 0), WROWS_ - 1);
        int swc0 = min(max(wc0, 0), WCOLS_ - 1), swc1 = min(max(wc1, 0), WCOLS_ - 1);
        int cb00 = (swr0 * WCOLS_ + swc0) * 8, sx00 = swc0 & 7;
        int cb01 = (swr0 * WCOLS_ + swc1) * 8, sx01 = swc1 & 7;
        int cb10 = (swr1 * WCOLS_ + swc0) * 8, sx10 = swc0 & 7;
        int cb11 = (swr1 * WCOLS_ + swc1) * 8, sx11 = swc1 & 7;
        int cy0 = min(max(y0, 0), H_ - 1), cy1 = min(max(y1, 0), H_ - 1);
        int cx0 = min(max(x0, 0), W_ - 1), cx1 = min(max(x1, 0), W_ - 1);

        #pragma unroll
        for (int half = 0; half < 2; ++half) {
            int s = k * 2 + half;
            int seg = half * 4 + kchunk;
            int cbg = half * 32 + kchunk * 8;
            ushortx8 v00 = win[cb00 + (seg ^ sx00)];
            ushortx8 v01 = win[cb01 + (seg ^ sx01)];
            ushortx8 v10 = win[cb10 + (seg ^ sx10)];
            ushortx8 v11 = win[cb11 + (seg ^ sx11)];
            if (q00 != 0.f && !in00)
                v00 = *reinterpret_cast<const ushortx8*>(xb + ((size_t)(cy0 * W_ + cx0) * 64 + cbg));
            if (q01 != 0.f && !in01)
                v01 = *reinterpret_cast<const ushortx8*>(xb + ((size_t)(cy0 * W_ + cx1) * 64 + cbg));
            if (q10 != 0.f && !in10)
                v10 = *reinterpret_cast<const ushortx8*>(xb + ((size_t)(cy1 * W_ + cx0) * 64 + cbg));
            if (q11 != 0.f && !in11)
                v11 = *reinterpret_cast<const ushortx8*>(xb + ((size_t)(cy1 * W_ + cx1) * 64 + cbg));
            union { unsigned short u[8]; bf16x8 v; } bu;
            #pragma unroll
            for (int j = 0; j < 8; ++j) {
                float v = q00 * bf2f(v00[j]) + q01 * bf2f(v01[j])
                        + q10 * bf2f(v10[j]) + q11 * bf2f(v11[j]);
                bu.u[j] = f2bf(v);
            }
            #pragma unroll
            for (int t = 0; t < 4; ++t) {
                bf16x8 afrag = *reinterpret_cast<const bf16x8*>(
                    wpack + ((size_t)(t * KSTEPS_ + s) * 64 + lane) * 8);
                acc[t] = __builtin_amdgcn_mfma_f32_16x16x32_bf16(afrag, bu.v, acc[t], 0, 0, 0);
            }
        }
    }

    unsigned short* zb = xdefb + (size_t)p * 64;
    #pragma unroll
    for (int t = 0; t < 4; ++t) {
        ushortx4 st;
        #pragma unroll
        for (int r = 0; r < 4; ++r) {
            int oc = t * 16 + kchunk * 4 + r;
            st[r] = f2bf(acc[t][r] + db[oc]);
        }
        *reinterpret_cast<ushortx4*>(zb + t * 16 + kchunk * 4) = st;
    }
}

// ---------------- fusion conv via MFMA + pre_mask blend --------------------
__global__ void __launch_bounds__(64) fuse_mfma(
        const unsigned short* __restrict__ xdefb,  // NHWC
        const unsigned short* __restrict__ wpf,
        const float* __restrict__ fb,
        const float* __restrict__ premask,
        const float* __restrict__ xin,             // NCHW
        float* __restrict__ out) {                 // NCHW
    int lane = threadIdx.x;
    int bid  = blockIdx.x;
    int row  = bid % H_;
    int rest = bid / H_;
    int tx   = rest % TX_;
    int b    = rest / TX_;
    int pq = lane & 15;
    int kchunk = lane >> 4;
    int h = row, w = tx * 16 + pq;
    int pix = row * W_ + w;
    int p = b * HW_ + pix;

    f32x4 acc[4];
    #pragma unroll
    for (int t = 0; t < 4; ++t) acc[t] = f32x4{0.f, 0.f, 0.f, 0.f};

    const unsigned short* xb = xdefb + (size_t)b * HW_ * 64;

    auto ldf = [&](int s) -> ushortx8 {
        const int k = s >> 1;
        const int dy = k / 3 - 1, dx = k % 3 - 1;
        bool ok = ((unsigned)(h + dy) < (unsigned)H_) &&
                  ((unsigned)(w + dx) < (unsigned)W_);
        int sp = ok ? (pix + dy * W_ + dx) : pix;
        int cbase = (s & 1) * 32 + kchunk * 8;
        return ok ? *reinterpret_cast<const ushortx8*>(xb + (size_t)sp * 64 + cbase)
                  : ushortx8{0, 0, 0, 0, 0, 0, 0, 0};
    };

    ushortx8 cb0 = ldf(0);
    ushortx8 cb1 = ldf(1);
    #pragma unroll
    for (int s = 0; s < KSTEPS_; ++s) {
        ushortx8 cur = (s & 1) ? cb1 : cb0;
        if (s + 2 < KSTEPS_) {
            if (s & 1) cb1 = ldf(s + 2); else cb0 = ldf(s + 2);
        }
        bf16x8 bv = __builtin_bit_cast(bf16x8, cur);
        #pragma unroll
        for (int t = 0; t < 4; ++t) {
            bf16x8 afrag = *reinterpret_cast<const bf16x8*>(
                wpf + ((size_t)(t * KSTEPS_ + s) * 64 + lane) * 8);
            acc[t] = __builtin_amdgcn_mfma_f32_16x16x32_bf16(afrag, bv, acc[t], 0, 0, 0);
        }
    }

    float pm = premask[(size_t)b * HW_ + pix];
    #pragma unroll
    for (int t = 0; t < 4; ++t) {
        #pragma unroll
        for (int r = 0; r < 4; ++r) {
            int oc = t * 16 + kchunk * 4 + r;
            size_t oidx = ((size_t)b * C_ + oc) * HW_ + pix;
            out[oidx] = (acc[t][r] + fb[oc]) * pm + xin[oidx] * (1.f - pm);
        }
    }
}

extern "C" void kernel_launch(void* const* d_in, const int* in_sizes, int n_in,
                              void* d_out, int out_size, void* d_ws, size_t ws_size,
                              hipStream_t stream) {
    const float* x       = (const float*)d_in[0];
    const float* premask = (const float*)d_in[1];
    const float* lnw     = (const float*)d_in[2];
    const float* lnb     = (const float*)d_in[3];
    const float* offw    = (const float*)d_in[4];
    const float* offb    = (const float*)d_in[5];
    const float* maskw   = (const float*)d_in[6];
    const float* maskb   = (const float*)d_in[7];
    const float* dw      = (const float*)d_in[8];
    const float* db      = (const float*)d_in[9];
    const float* fw      = (const float*)d_in[10];
    const float* fb      = (const float*)d_in[11];
    float* out = (float*)d_out;

    char* ws = (char*)d_ws;
    unsigned short* xnb   = (unsigned short*)ws;  ws += sizeof(short) * (size_t)BHW_ * 64;
    unsigned short* xdefb = (unsigned short*)ws;  ws += sizeof(short) * (size_t)BHW_ * 64;
    unsigned short* wpack = (unsigned short*)ws;  ws += sizeof(short) * 4 * KSTEPS_ * 64 * 8;
    unsigned short* wpf   = (unsigned short*)ws;  ws += sizeof(short) * 4 * KSTEPS_ * 64 * 8;
    unsigned short* wpc   = (unsigned short*)ws;  ws += sizeof(short) * 2 * KSTEPS_ * 64 * 8;

    ln_kernel<<<(BHW_ + 255) / 256, 256, 0, stream>>>(x, lnw, lnb, xnb);
    prepack_kernel<<<36, 256, 0, stream>>>(dw, fw, offw, maskw, wpack, wpf, wpc);
    dc_mfma<<<B_ * TX_ * (H_ / RG_), 256, 0, stream>>>(
        xnb, wpc, offb, maskb, wpack, db, xdefb);
    fuse_mfma<<<B_ * TX_ * H_, 64, 0, stream>>>(xdefb, wpf, fb, premask, x, out);
}

// Round 12
// 78.998 us; speedup vs baseline: 1.6879x; 1.2549x over previous
//
#include <hip/hip_runtime.h>
#include <hip/hip_bf16.h>
#include <math.h>

#define B_ 2
#define C_ 64
#define H_ 192
#define W_ 192
#define HW_ (H_*W_)
#define BHW_ (B_*HW_)
#define KK_ 9
#define CK_ (C_*KK_)      // 576
#define KSTEPS_ (CK_/32)  // 18
#define TX_ 12            // W_/16 column tiles
#define WROWS_ 8          // dc window rows (h0-2 .. h0+5)
#define WCOLS_ 21         // dc window cols (w0-2 .. w0+18)
#define WCHUNKS_ (WROWS_*WCOLS_*8)     // 1344
#define FWROWS_ 6         // fuse window rows (h0-1 .. h0+4)
#define FWCOLS_ 18        // fuse window cols (w0-1 .. w0+16)
#define FWCHUNKS_ (FWROWS_*FWCOLS_*8)  // 864

typedef __bf16 bf16x8 __attribute__((ext_vector_type(8)));
typedef float  f32x4  __attribute__((ext_vector_type(4)));
typedef unsigned short ushortx8 __attribute__((ext_vector_type(8)));
typedef unsigned short ushortx4 __attribute__((ext_vector_type(4)));

__device__ __forceinline__ float bf2f(unsigned short u) {
    unsigned int t = ((unsigned int)u) << 16;
    return __builtin_bit_cast(float, t);
}
__device__ __forceinline__ unsigned short f2bf(float f) {
    __hip_bfloat16 hb = __float2bfloat16(f);
    return *reinterpret_cast<unsigned short*>(&hb);
}

// ---------------- LayerNorm over channel axis -> bf16 NHWC ------------------
__global__ void ln_kernel(const float* __restrict__ x,
                          const float* __restrict__ lnw,
                          const float* __restrict__ lnb,
                          unsigned short* __restrict__ xnb) {   // [BHW][64]
    int p = blockIdx.x * blockDim.x + threadIdx.x;
    if (p >= BHW_) return;
    int b = p / HW_, pix = p % HW_;
    const float* xb = x + (size_t)b * C_ * HW_ + pix;
    float v[C_];
    float s = 0.f, s2 = 0.f;
    #pragma unroll
    for (int c = 0; c < C_; ++c) {
        v[c] = xb[(size_t)c * HW_];
        s += v[c]; s2 += v[c] * v[c];
    }
    float mu  = s * (1.0f / C_);
    float var = s2 * (1.0f / C_) - mu * mu;
    float inv = rsqrtf(var + 1e-5f);
    unsigned short* zb = xnb + (size_t)p * 64;
    #pragma unroll
    for (int g = 0; g < 8; ++g) {
        ushortx8 st;
        #pragma unroll
        for (int j = 0; j < 8; ++j) {
            int c = g * 8 + j;
            st[j] = f2bf((v[c] - mu) * inv * lnw[c] + lnb[c]);
        }
        *reinterpret_cast<ushortx8*>(zb + g * 8) = st;
    }
}

// ---------------- weight prepack (tap-outer ck = k*64+c) -------------------
__global__ void prepack_kernel(const float* __restrict__ dw,
                               const float* __restrict__ fw,
                               const float* __restrict__ offw,
                               const float* __restrict__ maskw,
                               unsigned short* __restrict__ wpack,
                               unsigned short* __restrict__ wpf,
                               unsigned short* __restrict__ wpc) {
    const int n1 = 4 * KSTEPS_ * 64 * 8;   // deform
    const int n2 = 4 * KSTEPS_ * 64 * 8;   // fusion
    const int n3 = 2 * KSTEPS_ * 64 * 8;   // conv27
    int gid = blockIdx.x * blockDim.x + threadIdx.x;
    int nth = gridDim.x * blockDim.x;
    for (int idx = gid; idx < n1 + n2 + n3; idx += nth) {
        int which = (idx < n1) ? 0 : (idx < n1 + n2 ? 1 : 2);
        int rem = idx - (which == 0 ? 0 : (which == 1 ? n1 : n1 + n2));
        int j = rem & 7;
        int l = (rem >> 3) & 63;
        int rest = rem >> 9;
        int s = rest % KSTEPS_;
        int t = rest / KSTEPS_;
        int oc = t * 16 + (l & 15);
        int ck = s * 32 + (l >> 4) * 8 + j;
        int k = ck >> 6, c = ck & 63;
        float v;
        if (which == 0) {
            v = dw[(size_t)oc * CK_ + c * 9 + k];
        } else if (which == 1) {
            v = fw[(size_t)oc * CK_ + c * 9 + k];
        } else {
            v = (oc < 18) ? offw[(size_t)oc * CK_ + c * 9 + k]
              : (oc < 27) ? maskw[(size_t)(oc - 18) * CK_ + c * 9 + k]
              : 0.f;
        }
        unsigned short u = f2bf(v);
        if (which == 0) wpack[rem] = u;
        else if (which == 1) wpf[rem] = u;
        else wpc[rem] = u;
    }
}

// ---------------- merged conv27 + deformable conv, M=32 per wave -----------
// 128-thread block = 2 waves; wave = 2 adjacent rows x 16 cols.
// Shared window rows h0-2..h0+5, cols w0-2..w0+18, seg^(col&7) swizzle.
__global__ void __launch_bounds__(128) dc_mfma(
        const unsigned short* __restrict__ xnb,   // NHWC
        const unsigned short* __restrict__ wpc,
        const float* __restrict__ offb, const float* __restrict__ maskb,
        const unsigned short* __restrict__ wpack,
        const float* __restrict__ db,
        unsigned short* __restrict__ xdefb) {     // NHWC
    __shared__ ushortx8 win[WCHUNKS_];    // 21504 B
    __shared__ float som[2][32][36];      // 9216 B (stride 36: 2-way alias)
    int tid  = threadIdx.x;
    int wave = tid >> 6;
    int lane = tid & 63;
    int bid  = blockIdx.x;
    int rg   = bid % (H_ / 4);
    int rest = bid / (H_ / 4);
    int tx   = rest % TX_;
    int b    = rest / TX_;
    int pq = lane & 15;
    int kchunk = lane >> 4;
    int h0 = rg * 4;
    int w0 = tx * 16, w = w0 + pq;
    int hh0 = h0 + 2 * wave, hh1 = hh0 + 1;

    const unsigned short* xb = xnb + (size_t)b * HW_ * 64;

    // ---- stage shared window ----
    #pragma unroll
    for (int i = 0; i < 11; ++i) {
        int idx = i * 128 + tid;
        if (idx < WCHUNKS_) {
            int r    = idx / (WCOLS_ * 8);
            int rem2 = idx - r * (WCOLS_ * 8);
            int c    = rem2 >> 3;
            int seg  = rem2 & 7;
            int gy = min(max(h0 - 2 + r, 0), H_ - 1);
            int gx = min(max(w0 - 2 + c, 0), W_ - 1);
            ushortx8 v = *reinterpret_cast<const ushortx8*>(
                xb + ((size_t)(gy * W_ + gx) * 64 + seg * 8));
            win[(r * WCOLS_ + c) * 8 + (seg ^ (c & 7))] = v;
        }
    }
    __syncthreads();

    // ---- phase 1: conv27 for both pixel rows (afrag shared) ----
    f32x4 cacc[2][2];
    #pragma unroll
    for (int pg = 0; pg < 2; ++pg)
        #pragma unroll
        for (int t = 0; t < 2; ++t) cacc[pg][t] = f32x4{0.f, 0.f, 0.f, 0.f};

    #pragma unroll
    for (int s = 0; s < KSTEPS_; ++s) {
        const int k = s >> 1;
        const int dy = k / 3 - 1, dxk = k % 3 - 1;
        int wc = pq + dxk + 2;
        int sidx = ((s & 1) * 4 + kchunk) ^ (wc & 7);
        bf16x8 bv[2];
        #pragma unroll
        for (int pg = 0; pg < 2; ++pg) {
            int hp = (pg ? hh1 : hh0);
            bool ok = ((unsigned)(hp + dy) < (unsigned)H_) &&
                      ((unsigned)(w + dxk) < (unsigned)W_);
            int wr = 2 * wave + pg + dy + 2;
            ushortx8 u = win[(wr * WCOLS_ + wc) * 8 + sidx];
            if (!ok) u = ushortx8{0, 0, 0, 0, 0, 0, 0, 0};
            bv[pg] = __builtin_bit_cast(bf16x8, u);
        }
        #pragma unroll
        for (int t = 0; t < 2; ++t) {
            bf16x8 afrag = *reinterpret_cast<const bf16x8*>(
                wpc + ((size_t)(t * KSTEPS_ + s) * 64 + lane) * 8);
            cacc[0][t] = __builtin_amdgcn_mfma_f32_16x16x32_bf16(afrag, bv[0], cacc[0][t], 0, 0, 0);
            cacc[1][t] = __builtin_amdgcn_mfma_f32_16x16x32_bf16(afrag, bv[1], cacc[1][t], 0, 0, 0);
        }
    }

    // bias / sigmoid -> per-wave som transpose slice (wave-private: no barrier)
    #pragma unroll
    for (int pg = 0; pg < 2; ++pg) {
        #pragma unroll
        for (int t = 0; t < 2; ++t) {
            f32x4 sv;
            #pragma unroll
            for (int r = 0; r < 4; ++r) {
                int oc = t * 16 + kchunk * 4 + r;
                float a = cacc[pg][t][r];
                if (oc < 18)      sv[r] = a + offb[oc];
                else if (oc < 27) sv[r] = 1.f / (1.f + expf(-(a + maskb[oc - 18])));
                else              sv[r] = 0.f;
            }
            *reinterpret_cast<f32x4*>(&som[wave][pg * 16 + pq][t * 16 + kchunk * 4]) = sv;
        }
    }

    const float* omA = som[wave][pq];
    const float* omB = som[wave][16 + pq];

    // ---- phase 2: bilinear gather (LDS) + MFMA, two pixel rows ----
    f32x4 acc[2][4];
    #pragma unroll
    for (int pg = 0; pg < 2; ++pg)
        #pragma unroll
        for (int t = 0; t < 4; ++t) acc[pg][t] = f32x4{0.f, 0.f, 0.f, 0.f};

    #pragma unroll
    for (int k = 0; k < KK_; ++k) {
        // per-row gather setup
        float qA[4], qB[4];
        int cbA[4], sxA[4], cbB[4], sxB[4];
        bool inA[4], inB[4];
        int gaA[4], gaB[4];
        #pragma unroll
        for (int pg = 0; pg < 2; ++pg) {
            const float* om = pg ? omB : omA;
            int hp = pg ? hh1 : hh0;
            float dy = om[2 * k], dx = om[2 * k + 1], m = om[18 + k];
            float py = dy + (float)(hp - 1 + k / 3);
            float px = dx + (float)(w - 1 + k % 3);
            float fy = floorf(py), fx = floorf(px);
            float ly = py - fy, lx = px - fx;
            int y0 = (int)fy, x0 = (int)fx;
            int y1 = y0 + 1, x1 = x0 + 1;
            bool oky0 = (unsigned)y0 < (unsigned)H_;
            bool oky1 = (unsigned)y1 < (unsigned)H_;
            bool okx0 = (unsigned)x0 < (unsigned)W_;
            bool okx1 = (unsigned)x1 < (unsigned)W_;
            float* q = pg ? qB : qA;
            q[0] = (oky0 && okx0) ? (1.f - ly) * (1.f - lx) * m : 0.f;
            q[1] = (oky0 && okx1) ? (1.f - ly) * lx * m : 0.f;
            q[2] = (oky1 && okx0) ? ly * (1.f - lx) * m : 0.f;
            q[3] = (oky1 && okx1) ? ly * lx * m : 0.f;
            int wr0 = y0 - (h0 - 2), wr1 = y1 - (h0 - 2);
            int wc0 = x0 - (w0 - 2), wc1 = x1 - (w0 - 2);
            bool inr0 = (unsigned)wr0 < (unsigned)WROWS_;
            bool inr1 = (unsigned)wr1 < (unsigned)WROWS_;
            bool inc0 = (unsigned)wc0 < (unsigned)WCOLS_;
            bool inc1 = (unsigned)wc1 < (unsigned)WCOLS_;
            bool* in = pg ? inB : inA;
            in[0] = inr0 && inc0; in[1] = inr0 && inc1;
            in[2] = inr1 && inc0; in[3] = inr1 && inc1;
            int swr0 = min(max(wr0, 0), WROWS_ - 1), swr1 = min(max(wr1, 0), WROWS_ - 1);
            int swc0 = min(max(wc0, 0), WCOLS_ - 1), swc1 = min(max(wc1, 0), WCOLS_ - 1);
            int* cb = pg ? cbB : cbA;
            int* sx = pg ? sxB : sxA;
            cb[0] = (swr0 * WCOLS_ + swc0) * 8; sx[0] = swc0 & 7;
            cb[1] = (swr0 * WCOLS_ + swc1) * 8; sx[1] = swc1 & 7;
            cb[2] = (swr1 * WCOLS_ + swc0) * 8; sx[2] = swc0 & 7;
            cb[3] = (swr1 * WCOLS_ + swc1) * 8; sx[3] = swc1 & 7;
            int cy0 = min(max(y0, 0), H_ - 1), cy1 = min(max(y1, 0), H_ - 1);
            int cx0 = min(max(x0, 0), W_ - 1), cx1 = min(max(x1, 0), W_ - 1);
            int* ga = pg ? gaB : gaA;
            ga[0] = cy0 * W_ + cx0; ga[1] = cy0 * W_ + cx1;
            ga[2] = cy1 * W_ + cx0; ga[3] = cy1 * W_ + cx1;
        }

        #pragma unroll
        for (int half = 0; half < 2; ++half) {
            int s = k * 2 + half;
            int seg = half * 4 + kchunk;
            int cbg = half * 32 + kchunk * 8;
            // A fragments (shared by both rows)
            bf16x8 af[4];
            #pragma unroll
            for (int t = 0; t < 4; ++t)
                af[t] = *reinterpret_cast<const bf16x8*>(
                    wpack + ((size_t)(t * KSTEPS_ + s) * 64 + lane) * 8);
            // corner values, row A then row B
            ushortx8 vA[4], vB[4];
            #pragma unroll
            for (int c = 0; c < 4; ++c) vA[c] = win[cbA[c] + (seg ^ sxA[c])];
            #pragma unroll
            for (int c = 0; c < 4; ++c) vB[c] = win[cbB[c] + (seg ^ sxB[c])];
            #pragma unroll
            for (int c = 0; c < 4; ++c) {
                if (qA[c] != 0.f && !inA[c])
                    vA[c] = *reinterpret_cast<const ushortx8*>(xb + ((size_t)gaA[c] * 64 + cbg));
                if (qB[c] != 0.f && !inB[c])
                    vB[c] = *reinterpret_cast<const ushortx8*>(xb + ((size_t)gaB[c] * 64 + cbg));
            }
            union { unsigned short u[8]; bf16x8 v; } buA, buB;
            #pragma unroll
            for (int j = 0; j < 8; ++j) {
                float a = qA[0] * bf2f(vA[0][j]) + qA[1] * bf2f(vA[1][j])
                        + qA[2] * bf2f(vA[2][j]) + qA[3] * bf2f(vA[3][j]);
                buA.u[j] = f2bf(a);
                float bvv = qB[0] * bf2f(vB[0][j]) + qB[1] * bf2f(vB[1][j])
                          + qB[2] * bf2f(vB[2][j]) + qB[3] * bf2f(vB[3][j]);
                buB.u[j] = f2bf(bvv);
            }
            #pragma unroll
            for (int t = 0; t < 4; ++t) {
                acc[0][t] = __builtin_amdgcn_mfma_f32_16x16x32_bf16(af[t], buA.v, acc[0][t], 0, 0, 0);
                acc[1][t] = __builtin_amdgcn_mfma_f32_16x16x32_bf16(af[t], buB.v, acc[1][t], 0, 0, 0);
            }
        }
    }

    #pragma unroll
    for (int pg = 0; pg < 2; ++pg) {
        int hp = pg ? hh1 : hh0;
        unsigned short* zb = xdefb + ((size_t)(b * HW_ + hp * W_ + w)) * 64;
        #pragma unroll
        for (int t = 0; t < 4; ++t) {
            ushortx4 st;
            #pragma unroll
            for (int r = 0; r < 4; ++r) {
                int oc = t * 16 + kchunk * 4 + r;
                st[r] = f2bf(acc[pg][t][r] + db[oc]);
            }
            *reinterpret_cast<ushortx4*>(zb + t * 16 + kchunk * 4) = st;
        }
    }
}

// ---------------- fusion conv via MFMA + pre_mask blend, M=32 --------------
__global__ void __launch_bounds__(128) fuse_mfma(
        const unsigned short* __restrict__ xdefb,  // NHWC
        const unsigned short* __restrict__ wpf,
        const float* __restrict__ fb,
        const float* __restrict__ premask,
        const float* __restrict__ xin,             // NCHW
        float* __restrict__ out) {                 // NCHW
    __shared__ ushortx8 fwin[FWCHUNKS_];  // 13824 B
    int tid  = threadIdx.x;
    int wave = tid >> 6;
    int lane = tid & 63;
    int bid  = blockIdx.x;
    int rg   = bid % (H_ / 4);
    int rest = bid / (H_ / 4);
    int tx   = rest % TX_;
    int b    = rest / TX_;
    int pq = lane & 15;
    int kchunk = lane >> 4;
    int h0 = rg * 4;
    int w0 = tx * 16, w = w0 + pq;
    int hh0 = h0 + 2 * wave, hh1 = hh0 + 1;

    const unsigned short* xb = xdefb + (size_t)b * HW_ * 64;

    // ---- stage window rows h0-1..h0+4, cols w0-1..w0+16 ----
    #pragma unroll
    for (int i = 0; i < 7; ++i) {
        int idx = i * 128 + tid;
        if (idx < FWCHUNKS_) {
            int r    = idx / (FWCOLS_ * 8);
            int rem2 = idx - r * (FWCOLS_ * 8);
            int c    = rem2 >> 3;
            int seg  = rem2 & 7;
            int gy = min(max(h0 - 1 + r, 0), H_ - 1);
            int gx = min(max(w0 - 1 + c, 0), W_ - 1);
            ushortx8 v = *reinterpret_cast<const ushortx8*>(
                xb + ((size_t)(gy * W_ + gx) * 64 + seg * 8));
            fwin[(r * FWCOLS_ + c) * 8 + (seg ^ (c & 7))] = v;
        }
    }
    __syncthreads();

    f32x4 acc[2][4];
    #pragma unroll
    for (int pg = 0; pg < 2; ++pg)
        #pragma unroll
        for (int t = 0; t < 4; ++t) acc[pg][t] = f32x4{0.f, 0.f, 0.f, 0.f};

    #pragma unroll
    for (int s = 0; s < KSTEPS_; ++s) {
        const int k = s >> 1;
        const int dy = k / 3 - 1, dxk = k % 3 - 1;
        int wc = pq + dxk + 1;
        int sidx = ((s & 1) * 4 + kchunk) ^ (wc & 7);
        bf16x8 bv[2];
        #pragma unroll
        for (int pg = 0; pg < 2; ++pg) {
            int hp = (pg ? hh1 : hh0);
            bool ok = ((unsigned)(hp + dy) < (unsigned)H_) &&
                      ((unsigned)(w + dxk) < (unsigned)W_);
            int wr = 2 * wave + pg + dy + 1;
            ushortx8 u = fwin[(wr * FWCOLS_ + wc) * 8 + sidx];
            if (!ok) u = ushortx8{0, 0, 0, 0, 0, 0, 0, 0};
            bv[pg] = __builtin_bit_cast(bf16x8, u);
        }
        #pragma unroll
        for (int t = 0; t < 4; ++t) {
            bf16x8 afrag = *reinterpret_cast<const bf16x8*>(
                wpf + ((size_t)(t * KSTEPS_ + s) * 64 + lane) * 8);
            acc[0][t] = __builtin_amdgcn_mfma_f32_16x16x32_bf16(afrag, bv[0], acc[0][t], 0, 0, 0);
            acc[1][t] = __builtin_amdgcn_mfma_f32_16x16x32_bf16(afrag, bv[1], acc[1][t], 0, 0, 0);
        }
    }

    #pragma unroll
    for (int pg = 0; pg < 2; ++pg) {
        int hp = pg ? hh1 : hh0;
        int pix = hp * W_ + w;
        float pm = premask[(size_t)b * HW_ + pix];
        #pragma unroll
        for (int t = 0; t < 4; ++t) {
            #pragma unroll
            for (int r = 0; r < 4; ++r) {
                int oc = t * 16 + kchunk * 4 + r;
                size_t oidx = ((size_t)b * C_ + oc) * HW_ + pix;
                out[oidx] = (acc[pg][t][r] + fb[oc]) * pm + xin[oidx] * (1.f - pm);
            }
        }
    }
}

extern "C" void kernel_launch(void* const* d_in, const int* in_sizes, int n_in,
                              void* d_out, int out_size, void* d_ws, size_t ws_size,
                              hipStream_t stream) {
    const float* x       = (const float*)d_in[0];
    const float* premask = (const float*)d_in[1];
    const float* lnw     = (const float*)d_in[2];
    const float* lnb     = (const float*)d_in[3];
    const float* offw    = (const float*)d_in[4];
    const float* offb    = (const float*)d_in[5];
    const float* maskw   = (const float*)d_in[6];
    const float* maskb   = (const float*)d_in[7];
    const float* dw      = (const float*)d_in[8];
    const float* db      = (const float*)d_in[9];
    const float* fw      = (const float*)d_in[10];
    const float* fb      = (const float*)d_in[11];
    float* out = (float*)d_out;

    char* ws = (char*)d_ws;
    unsigned short* xnb   = (unsigned short*)ws;  ws += sizeof(short) * (size_t)BHW_ * 64;
    unsigned short* xdefb = (unsigned short*)ws;  ws += sizeof(short) * (size_t)BHW_ * 64;
    unsigned short* wpack = (unsigned short*)ws;  ws += sizeof(short) * 4 * KSTEPS_ * 64 * 8;
    unsigned short* wpf   = (unsigned short*)ws;  ws += sizeof(short) * 4 * KSTEPS_ * 64 * 8;
    unsigned short* wpc   = (unsigned short*)ws;  ws += sizeof(short) * 2 * KSTEPS_ * 64 * 8;

    const int grid = B_ * TX_ * (H_ / 4);   // 1152 two-wave blocks

    ln_kernel<<<(BHW_ + 255) / 256, 256, 0, stream>>>(x, lnw, lnb, xnb);
    prepack_kernel<<<36, 256, 0, stream>>>(dw, fw, offw, maskw, wpack, wpf, wpc);
    dc_mfma<<<grid, 128, 0, stream>>>(
        xnb, wpc, offb, maskb, wpack, db, xdefb);
    fuse_mfma<<<grid, 128, 0, stream>>>(xdefb, wpf, fb, premask, x, out);
}